// Round 18
// baseline (126.062 us; speedup 1.0000x reference)
//
#include <hip/hip_runtime.h>

typedef __attribute__((ext_vector_type(8))) short short8;
typedef __attribute__((ext_vector_type(4))) float f32x4;
typedef __attribute__((ext_vector_type(16))) float f32x16;
typedef __attribute__((ext_vector_type(4))) int i32x4;

__device__ __forceinline__ unsigned short f2bf(float f){
  union { float f; unsigned int u; } cv; cv.f = f;
  unsigned int u = cv.u;
  u = (u + 0x7fffu + ((u >> 16) & 1u)) >> 16;
  return (unsigned short)u;
}
__device__ __forceinline__ float bf2f(unsigned short h){
  union { unsigned int u; float f; } cv; cv.u = ((unsigned int)h) << 16;
  return cv.f;
}

typedef unsigned int u32g __attribute__((address_space(1)));
typedef unsigned int u32l __attribute__((address_space(3)));
__device__ __forceinline__ void gload16(const void* g, void* l){
  __builtin_amdgcn_global_load_lds((const u32g*)g, (u32l*)l, 16, 0, 0);
}

__device__ __forceinline__ unsigned int cvt2_fp8(float a, float b){
  unsigned int r;
  asm("v_cvt_pk_fp8_f32 %0, %1, %2" : "=v"(r) : "v"(a), "v"(b));
  return r;
}

#define BARRIER() asm volatile("s_barrier" ::: "memory")
#define WAITV(N)  asm volatile("s_waitcnt vmcnt(" #N ")" ::: "memory")

// ---------------- fused: per-batch partial reduction (blocks 0..255) + weight convert (256..1279) ----
__global__ __launch_bounds__(256) void fused_pre_k(const float* __restrict__ x,
                                                   float2* __restrict__ partial,
                                                   const float* __restrict__ qkv_w,
                                                   const float* __restrict__ qkv_b,
                                                   const float* __restrict__ proj_w,
                                                   unsigned short* __restrict__ Wqk,
                                                   unsigned short* __restrict__ Wv,
                                                   unsigned short* __restrict__ Wp,
                                                   float* __restrict__ bias_qkv){
  const int blk = blockIdx.x;
  if (blk < 256){
    const int b = blk >> 6, xb = blk & 63;
    const float4* xp = (const float4*)(x + (size_t)b*1048576 + (size_t)xb*16384);
    float s = 0.f, sq = 0.f;
    #pragma unroll
    for (int i = 0; i < 16; ++i){
      float4 v = xp[threadIdx.x + i*256];
      s  += v.x + v.y + v.z + v.w;
      sq += v.x*v.x + v.y*v.y + v.z*v.z + v.w*v.w;
    }
    #pragma unroll
    for (int m = 1; m < 64; m <<= 1){ s += __shfl_xor(s, m); sq += __shfl_xor(sq, m); }
    __shared__ float2 acc[4];
    if ((threadIdx.x & 63) == 0) acc[threadIdx.x >> 6] = make_float2(s, sq);
    __syncthreads();
    if (threadIdx.x == 0){
      float S = 0.f, Q = 0.f;
      for (int i = 0; i < 4; ++i){ S += acc[i].x; Q += acc[i].y; }
      partial[b*64 + xb] = make_float2(S, Q);
    }
  } else {
    int id = (blk - 256) * 256 + threadIdx.x;
    if (id < 131072){
      Wqk[id] = f2bf(qkv_w[id]);
      if (id < 768) bias_qkv[id] = qkv_b[id];
    } else if (id < 196608){
      Wv[id - 131072] = f2bf(qkv_w[id]);
    } else {
      int j = id - 196608;
      Wp[j] = f2bf(proj_w[j]);
    }
  }
}

// ---------------- GroupNorm + transpose (final stat reduce done per-block, redundantly) ----------
__global__ __launch_bounds__(256) void norm_transpose_k(const float* __restrict__ x,
                                                        const float* __restrict__ gamma,
                                                        const float* __restrict__ beta,
                                                        const float2* __restrict__ partial,
                                                        unsigned short* __restrict__ xnt){
  __shared__ float tile[64][65];
  __shared__ float2 stt;
  const int b = blockIdx.z, n0 = blockIdx.x*64, c0 = blockIdx.y*64;
  const int t = threadIdx.x;
  if (t < 64){
    float2 p = partial[b*64 + t];
    float s = p.x, q = p.y;
    #pragma unroll
    for (int m = 1; m < 64; m <<= 1){ s += __shfl_xor(s, m); q += __shfl_xor(q, m); }
    if (t == 0){
      const float inv = 1.0f/1048576.0f;
      float mean = s*inv;
      float var  = q*inv - mean*mean;
      stt = make_float2(mean, rsqrtf(var + 1e-6f));
    }
  }
  __syncthreads();
  const float2 st = stt;
  const int col = t & 63, rb = t >> 6;
  #pragma unroll
  for (int i = 0; i < 16; ++i){
    int rr = i*4 + rb;
    float xv = x[((size_t)b*256 + c0 + rr)*4096 + n0 + col];
    tile[rr][col] = (xv - st.x) * st.y * gamma[c0+rr] + beta[c0+rr];
  }
  __syncthreads();
  #pragma unroll
  for (int i = 0; i < 16; ++i){
    int nr = i*4 + rb;
    xnt[((size_t)b*4096 + n0 + nr)*256 + c0 + col] = f2bf(tile[col][nr]);
  }
}

// ---------------- NT GEMM (global_load_lds staging, dbuf, 1 barrier/K-step) ----------------
// vtile==3 (fused QKV): gn<512 -> fp8 qk8[b][gm][gn] (ldc=512); gn>=512 -> fp8 V A-frag tile
//   with c=gn-512, n=gm: vt8[b*1MB + ((n>>4)*8 + (c>>5))*512 + (((c&31)*16 + (n&15)) ^ ((c>>3&1)<<3))]
__global__ __launch_bounds__(256) void gemm_nt_k(const unsigned short* __restrict__ A,
                                                 const unsigned short* __restrict__ B,
                                                 int lda, int ldb, long sA, long sB,
                                                 const float* __restrict__ bias_m,
                                                 const float* __restrict__ bias_n,
                                                 const float* __restrict__ resid, long sR,
                                                 float* __restrict__ outF,
                                                 unsigned short* __restrict__ outB,
                                                 unsigned char* __restrict__ out8,
                                                 unsigned char* __restrict__ out8v,
                                                 int ldc, long sC, int vtile){
  __shared__ __align__(16) char gs[16384];   // dbuf 2 x (A 4KB | B 4KB); 64B rows, XOR 16B slots
  const int b  = blockIdx.z;
  const int m0 = blockIdx.x * 64, n0 = blockIdx.y * 64;
  const unsigned short* Ab = A + (size_t)b * sA;
  const unsigned short* Bb = B + (size_t)b * sB;
  const int t = threadIdx.x;
  const int lane = t & 63, w = t >> 6;
  const int g = lane >> 4, r = lane & 15;
  const int wm = (w >> 1) * 32, wn = (w & 1) * 32;
  // staging: source col-slot pre-swizzled so LDS element (row, slot) holds src slot (slot ^ (row&3))
  const int srow = lane >> 2;                     // row within 16-row chunk (row&3 == srow&3)
  const int scol = ((lane & 3) ^ (srow & 3)) * 8; // swizzled source column (bf16 units)
  auto stage = [&](int ks, int half){
    char* buf = gs + half*8192;
    if (w < 2){
      #pragma unroll
      for (int i = 0; i < 2; ++i){
        int m = w*32 + i*16 + srow;
        gload16(Ab + (size_t)(m0 + m)*lda + ks*32 + scol, buf + w*2048 + i*1024);
      }
    } else {
      #pragma unroll
      for (int i = 0; i < 2; ++i){
        int n = (w-2)*32 + i*16 + srow;
        gload16(Bb + (size_t)(n0 + n)*ldb + ks*32 + scol, buf + 4096 + (w-2)*2048 + i*1024);
      }
    }
  };
  stage(0, 0);
  f32x4 acc00 = {0,0,0,0}, acc01 = {0,0,0,0}, acc10 = {0,0,0,0}, acc11 = {0,0,0,0};
  const int sa = (g ^ (r & 3)) << 4;   // fragment slot swizzle (row&3 == r&3 for all rows used)
  for (int ks = 0; ks < 8; ++ks){
    WAITV(0);
    BARRIER();
    if (ks < 7) stage(ks + 1, (ks + 1) & 1);
    const char* Abuf = gs + (ks & 1)*8192;
    const char* Bbuf = Abuf + 4096;
    short8 af0 = *(const short8*)(Abuf + (wm + r)*64 + sa);
    short8 af1 = *(const short8*)(Abuf + (wm + 16 + r)*64 + sa);
    short8 bf0 = *(const short8*)(Bbuf + (wn + r)*64 + sa);
    short8 bf1 = *(const short8*)(Bbuf + (wn + 16 + r)*64 + sa);
    acc00 = __builtin_amdgcn_mfma_f32_16x16x32_bf16(af0, bf0, acc00, 0, 0, 0);
    acc01 = __builtin_amdgcn_mfma_f32_16x16x32_bf16(af0, bf1, acc01, 0, 0, 0);
    acc10 = __builtin_amdgcn_mfma_f32_16x16x32_bf16(af1, bf0, acc10, 0, 0, 0);
    acc11 = __builtin_amdgcn_mfma_f32_16x16x32_bf16(af1, bf1, acc11, 0, 0, 0);
  }
  f32x4 accs[2][2] = {{acc00, acc01},{acc10, acc11}};
  #pragma unroll
  for (int mi = 0; mi < 2; ++mi)
    #pragma unroll
    for (int ni = 0; ni < 2; ++ni)
      #pragma unroll
      for (int j = 0; j < 4; ++j){
        int gm = m0 + wm + mi*16 + g*4 + j;
        int gn = n0 + wn + ni*16 + r;
        float vv = accs[mi][ni][j];
        if (bias_m) vv += bias_m[gm];
        if (bias_n) vv += bias_n[gn];
        if (resid)  vv += resid[(size_t)b*sR + (size_t)gm*ldc + gn];
        if (out8){
          unsigned char v8 = (unsigned char)(cvt2_fp8(vv, vv) & 0xff);
          if (vtile == 3 && gn >= 512){
            int c = gn - 512, n = gm;
            int inner = (((c & 31)*16 + (n & 15)) ^ (((c >> 3) & 1) << 3));
            out8v[(size_t)b*1048576 + (size_t)((n >> 4)*8 + (c >> 5))*512 + inner] = v8;
          } else {
            out8[(size_t)b*sC + (size_t)gm*ldc + gn] = v8;
          }
        } else if (outB){
          outB[(size_t)b*sC + (size_t)gm*ldc + gn] = f2bf(vv);
        } else {
          outF[(size_t)b*sC + (size_t)gm*ldc + gn] = vv;
        }
      }
}

// ---------------- flash attention: 4 waves x (32 q, full 32-k, 256 c); fp8 QK AND fp8 PV ----------
// qk8[b][n][512B] fp8 (Q 0..255, K 256..511); vt8 fp8 V A-frag tiles [k/16][c/32][32][16].
// p = exp2(S*scale) (no max, constant cancels). P packed to fp8 in-register. KVBLK=32,
// ksplit=4, 512 blocks (2/CU), 32 iters, 1 barrier + 1 vmcnt per iter, LDS 32KB.
__global__ __launch_bounds__(256, 2) void attn_k(const unsigned char* __restrict__ qk8,
                                                 const unsigned char* __restrict__ vt8,
                                                 unsigned short* __restrict__ po,
                                                 float* __restrict__ ml){
  __shared__ __align__(16) char smem[32768];   // dbuf 2 x (K 8KB | V 8KB)
  const int id = blockIdx.x;
  const int combo = id & 15, qb = id >> 4;     // combo&7 -> XCD (K/V L2-resident per combo)
  const int b = combo >> 2, ks = combo & 3;
  const int q0 = qb * 128;
  const int t = threadIdx.x, lane = t & 63, w = t >> 6;   // w = q-subblock 0..3
  const int hi = lane >> 5, l31 = lane & 31;
  const unsigned char* qkb = qk8 + (size_t)b * 4096 * 512;
  const unsigned char* vtb = vt8 + (size_t)b * 1048576;
  const float SQL2 = 0.0625f * 1.44269504088896340736f;

  // ---- Q fp8 fragments: wave owns q-rows q0 + w*32 + l31 (B-operand) ----
  unsigned long long qf[16];
  {
    const unsigned char* qrow = qkb + (size_t)(q0 + w*32 + l31) * 512;
    #pragma unroll
    for (int s = 0; s < 16; ++s) qf[s] = *(const unsigned long long*)(qrow + s*16 + hi*8);
  }

  // stage K tile (32 rows x 256B fp8): 2 loads/thread, XOR-swizzled source, linear dest
  auto stageK = [&](int kt, char* buf){
    const int kbase = ks*1024 + kt*32;
    #pragma unroll
    for (int i2 = 0; i2 < 2; ++i2){
      int ci = (w*2 + i2)*64 + lane;
      int r = ci >> 4;
      const unsigned char* src = qkb + (size_t)(kbase + r)*512 + 256
                               + (((ci & 15) ^ (r & 15)) * 16);
      gload16(src, buf + (w*2 + i2)*1024);
    }
  };
  // stage V (16 fp8 tiles of 512B): 2 loads/thread (each load covers 2 tiles)
  auto stageV = [&](int kt, char* buf){
    const int kbase = ks*1024 + kt*32;
    #pragma unroll
    for (int i = 0; i < 2; ++i){
      int tp = (w*2 + i)*2;              // first tile of this 1KB pair
      int tile = tp + (lane >> 5);       // kslice = tile>>3, c-block = tile&7
      const unsigned char* src = vtb + (size_t)((kbase >> 4) + (tile >> 3))*4096
                               + (tile & 7)*512 + (lane & 31)*16;
      gload16(src, buf + 8192 + tp*512);
    }
  };
  stageK(0, smem);
  stageV(0, smem);

  f32x16 O[8];     // full 256 c for this wave's 32 q
  #pragma unroll
  for (int cb = 0; cb < 8; ++cb)
    #pragma unroll
    for (int jj = 0; jj < 16; ++jj) O[cb][jj] = 0.f;
  float lrun = 0.f;
  const int ksw = (l31 & 15) << 4;
  const int vsw = ((l31 >> 3) & 1) << 3;
  const int vbase = l31*16 + hi*8;

  for (int kt = 0; kt < 32; ++kt){
    char* cur = smem + (kt & 1)*16384;
    char* nxt = smem + ((kt + 1) & 1)*16384;

    WAITV(0);     // tile-kt stages landed (issued a full iteration ago)
    BARRIER();    // all waves' tile kt visible; prev buffer fully consumed

    int ktn = (kt < 31) ? kt + 1 : 31;
    stageK(ktn, nxt);   // issue next tile now: covered by QK + SM + PV
    stageV(ktn, nxt);

    // ---- S^T = K . Q : 16 fp8 MFMA, 2 chains (full 32 k-rows) ----
    f32x16 Sa, Sb;
    #pragma unroll
    for (int jj = 0; jj < 16; ++jj){ Sa[jj] = 0.f; Sb[jj] = 0.f; }
    const char* kp = cur + l31*256;
    __builtin_amdgcn_s_setprio(1);
    #pragma unroll
    for (int s = 0; s < 8; ++s){
      unsigned long long k0 = *(const unsigned long long*)(kp + (((2*s  )*16 + hi*8) ^ ksw));
      unsigned long long k1 = *(const unsigned long long*)(kp + (((2*s+1)*16 + hi*8) ^ ksw));
      Sa = __builtin_amdgcn_mfma_f32_32x32x16_fp8_fp8((long long)k0, (long long)qf[2*s  ], Sa, 0, 0, 0);
      Sb = __builtin_amdgcn_mfma_f32_32x32x16_fp8_fp8((long long)k1, (long long)qf[2*s+1], Sb, 0, 0, 0);
    }
    __builtin_amdgcn_s_setprio(0);

    // ---- softmax (no max; constant cancels): p = exp2(S*scale), pack to fp8 ----
    float p[16];
    #pragma unroll
    for (int jj = 0; jj < 16; ++jj)
      p[jj] = __builtin_amdgcn_exp2f((Sa[jj] + Sb[jj]) * SQL2);
    lrun += ((p[0]+p[1]) + (p[2]+p[3])) + ((p[4]+p[5]) + (p[6]+p[7]))
          + ((p[8]+p[9]) + (p[10]+p[11])) + ((p[12]+p[13]) + (p[14]+p[15]));
    unsigned A0 = (unsigned)__builtin_amdgcn_cvt_pk_fp8_f32(p[0],  p[1],  0, false);
    A0 = (unsigned)__builtin_amdgcn_cvt_pk_fp8_f32(p[2],  p[3],  (int)A0, true);
    unsigned B0 = (unsigned)__builtin_amdgcn_cvt_pk_fp8_f32(p[4],  p[5],  0, false);
    B0 = (unsigned)__builtin_amdgcn_cvt_pk_fp8_f32(p[6],  p[7],  (int)B0, true);
    unsigned A1 = (unsigned)__builtin_amdgcn_cvt_pk_fp8_f32(p[8],  p[9],  0, false);
    A1 = (unsigned)__builtin_amdgcn_cvt_pk_fp8_f32(p[10], p[11], (int)A1, true);
    unsigned B1 = (unsigned)__builtin_amdgcn_cvt_pk_fp8_f32(p[12], p[13], 0, false);
    B1 = (unsigned)__builtin_amdgcn_cvt_pk_fp8_f32(p[14], p[15], (int)B1, true);
    asm("v_permlane32_swap_b32 %0, %1" : "+v"(A0), "+v"(B0));
    asm("v_permlane32_swap_b32 %0, %1" : "+v"(A1), "+v"(B1));
    long long pb0 = (long long)(((unsigned long long)B0 << 32) | A0);  // k 0..15
    long long pb1 = (long long)(((unsigned long long)B1 << 32) | A1);  // k 16..31

    // ---- O += V . P^T : 8 c-blocks x 2 k-slices, all fp8 ----
    const char* Vt = cur + 8192;
    __builtin_amdgcn_s_setprio(1);
    #pragma unroll
    for (int cb = 0; cb < 8; ++cb){
      unsigned long long v0 = *(const unsigned long long*)(Vt + (0*8 + cb)*512 + (vbase ^ vsw));
      O[cb] = __builtin_amdgcn_mfma_f32_32x32x16_fp8_fp8((long long)v0, pb0, O[cb], 0, 0, 0);
      unsigned long long v1 = *(const unsigned long long*)(Vt + (1*8 + cb)*512 + (vbase ^ vsw));
      O[cb] = __builtin_amdgcn_mfma_f32_32x32x16_fp8_fp8((long long)v1, pb1, O[cb], 0, 0, 0);
    }
    __builtin_amdgcn_s_setprio(0);
  }
  WAITV(0);   // drain tail stages before endpgm

  // ---- epilogue: unnormalized partials + l partials (wave owns full O) ----
  float lf = lrun + __shfl_xor(lrun, 32);
  const int qg = q0 + w*32 + l31;
  unsigned short* pob = po + (size_t)combo * 1048576;   // [256 c][4096 q]
  #pragma unroll
  for (int cb = 0; cb < 8; ++cb)
    #pragma unroll
    for (int jj = 0; jj < 16; ++jj){
      int c = cb*32 + (jj & 3) + 8*(jj >> 2) + 4*hi;
      pob[(size_t)c*4096 + qg] = f2bf(O[cb][jj]);
    }
  if (lane < 32)
    ml[(size_t)combo*4096 + qg] = lf;
}

// ---------------- merge the 4 k-chunks: out ho[b][q][c] bf16 ----------------
__global__ __launch_bounds__(256) void attn_merge_k(const unsigned short* __restrict__ po,
                                                    const float* __restrict__ ml,
                                                    unsigned short* __restrict__ ho){
  __shared__ float Of[64][261];
  const int b = blockIdx.y, q0 = blockIdx.x * 64;
  const int t = threadIdx.x, ql = t & 63, ci = t >> 6;
  const int q = q0 + ql;
  float L = 0.f;
  #pragma unroll
  for (int ksv = 0; ksv < 4; ++ksv)
    L += ml[(size_t)(b*4 + ksv)*4096 + q];
  float inv = 1.0f / L;
  float acc[64];
  #pragma unroll
  for (int i = 0; i < 64; ++i) acc[i] = 0.f;
  #pragma unroll
  for (int ksv = 0; ksv < 4; ++ksv){
    const unsigned short* pb = po + (size_t)(b*4 + ksv)*1048576 + q;
    #pragma unroll
    for (int i = 0; i < 64; ++i)
      acc[i] += bf2f(pb[(size_t)(ci + 4*i)*4096]);
  }
  #pragma unroll
  for (int i = 0; i < 64; ++i) Of[ql][ci + 4*i] = acc[i] * inv;
  __syncthreads();
  const int qr = t >> 2, sub = t & 3;
  const float* rowp = Of[qr];
  unsigned short* dst = ho + ((size_t)(b*4096 + q0 + qr))*256;
  #pragma unroll
  for (int jj = 0; jj < 8; ++jj){
    int c = sub*8 + jj*32;
    float4 v0 = *(const float4*)(rowp + c);
    float4 v1 = *(const float4*)(rowp + c + 4);
    short8 o;
    o[0] = (short)f2bf(v0.x); o[1] = (short)f2bf(v0.y);
    o[2] = (short)f2bf(v0.z); o[3] = (short)f2bf(v0.w);
    o[4] = (short)f2bf(v1.x); o[5] = (short)f2bf(v1.y);
    o[6] = (short)f2bf(v1.z); o[7] = (short)f2bf(v1.w);
    *(short8*)(dst + c) = o;
  }
}

// ---------------- launch ----------------
extern "C" void kernel_launch(void* const* d_in, const int* in_sizes, int n_in,
                              void* d_out, int out_size, void* d_ws, size_t ws_size,
                              hipStream_t stream){
  const float* x      = (const float*)d_in[0];
  const float* gamma  = (const float*)d_in[1];
  const float* beta   = (const float*)d_in[2];
  const float* qkv_w  = (const float*)d_in[3];
  const float* qkv_b  = (const float*)d_in[4];
  const float* proj_w = (const float*)d_in[5];
  const float* proj_b = (const float*)d_in[6];
  float* out = (float*)d_out;
  char* ws = (char*)d_ws;

  float2* partial        = (float2*)(ws + 0);
  float*  bias_qkv       = (float*)(ws + 4096);               // 768 f32
  unsigned short* Wqk    = (unsigned short*)(ws + 8192);      // 512x256 bf16 (contiguous with Wv)
  unsigned short* Wv     = (unsigned short*)(ws + 270336);    // 256x256
  unsigned short* Wp     = (unsigned short*)(ws + 401408);    // 256x256
  unsigned short* xnt    = (unsigned short*)(ws + 532480);    // 4x4096x256 bf16 (8.4 MB)
  unsigned char*  qk8    = (unsigned char*)(ws + 8921088);    // 4x4096x512 fp8 (8.4 MB)
  unsigned char*  vt8    = (unsigned char*)(ws + 17309696);   // 4x1MB fp8 V tiles (4.2 MB)
  unsigned short* po     = (unsigned short*)(ws + 25698304);  // 16x256x4096 bf16 (33.6 MB)
  float*          ml     = (float*)(ws + 59252736);           // 16x4096 f32 (256 KB)
  unsigned short* ho     = xnt;  // xnt dead after QKV gemm -> reuse

  fused_pre_k<<<1280, 256, 0, stream>>>(x, partial, qkv_w, qkv_b, proj_w,
                                        Wqk, Wv, Wp, bias_qkv);
  norm_transpose_k<<<dim3(64,4,4), 256, 0, stream>>>(x, gamma, beta, partial, xnt);
  // fused q,k,v GEMM: N=768 (gn<512 -> qk8, gn>=512 -> vt8 tiles); single pass over xnt
  gemm_nt_k<<<dim3(64,12,4), 256, 0, stream>>>(xnt, Wqk, 256, 256, 4096L*256, 0,
      nullptr, bias_qkv, nullptr, 0, nullptr, nullptr, qk8, vt8, 512, 4096L*512, 3);
  attn_k<<<dim3(512), 256, 0, stream>>>(qk8, vt8, po, ml);
  attn_merge_k<<<dim3(64,4), 256, 0, stream>>>(po, ml, ho);
  // out = proj(ho) + x
  gemm_nt_k<<<dim3(4,64,4), 256, 0, stream>>>(Wp, ho, 256, 256, 0, 4096L*256,
      proj_b, nullptr, x, 1048576L, out, nullptr, nullptr, nullptr, 4096, 1048576L, 0);
}

// Round 19
// 113.087 us; speedup vs baseline: 1.1147x; 1.1147x over previous
//
#include <hip/hip_runtime.h>

typedef __attribute__((ext_vector_type(8))) short short8;
typedef __attribute__((ext_vector_type(4))) float f32x4;
typedef __attribute__((ext_vector_type(16))) float f32x16;
typedef __attribute__((ext_vector_type(4))) int i32x4;

__device__ __forceinline__ unsigned short f2bf(float f){
  union { float f; unsigned int u; } cv; cv.f = f;
  unsigned int u = cv.u;
  u = (u + 0x7fffu + ((u >> 16) & 1u)) >> 16;
  return (unsigned short)u;
}
__device__ __forceinline__ float bf2f(unsigned short h){
  union { unsigned int u; float f; } cv; cv.u = ((unsigned int)h) << 16;
  return cv.f;
}

typedef unsigned int u32g __attribute__((address_space(1)));
typedef unsigned int u32l __attribute__((address_space(3)));
__device__ __forceinline__ void gload16(const void* g, void* l){
  __builtin_amdgcn_global_load_lds((const u32g*)g, (u32l*)l, 16, 0, 0);
}

__device__ __forceinline__ unsigned int cvtpk_bf16(float lo, float hi){
  unsigned int r;
  asm("v_cvt_pk_bf16_f32 %0, %1, %2" : "=v"(r) : "v"(lo), "v"(hi));
  return r;
}
__device__ __forceinline__ unsigned int cvt2_fp8(float a, float b){
  unsigned int r;
  asm("v_cvt_pk_fp8_f32 %0, %1, %2" : "=v"(r) : "v"(a), "v"(b));
  return r;
}

#define BARRIER() asm volatile("s_barrier" ::: "memory")
#define WAITV(N)  asm volatile("s_waitcnt vmcnt(" #N ")" ::: "memory")

// ---------------- fused: per-batch partial reduction (blocks 0..255) + weight convert (256..1279) ----
__global__ __launch_bounds__(256) void fused_pre_k(const float* __restrict__ x,
                                                   float2* __restrict__ partial,
                                                   const float* __restrict__ qkv_w,
                                                   const float* __restrict__ qkv_b,
                                                   const float* __restrict__ proj_w,
                                                   unsigned short* __restrict__ Wqk,
                                                   unsigned short* __restrict__ Wv,
                                                   unsigned short* __restrict__ Wp,
                                                   float* __restrict__ bias_qkv){
  const int blk = blockIdx.x;
  if (blk < 256){
    const int b = blk >> 6, xb = blk & 63;
    const float4* xp = (const float4*)(x + (size_t)b*1048576 + (size_t)xb*16384);
    float s = 0.f, sq = 0.f;
    #pragma unroll
    for (int i = 0; i < 16; ++i){
      float4 v = xp[threadIdx.x + i*256];
      s  += v.x + v.y + v.z + v.w;
      sq += v.x*v.x + v.y*v.y + v.z*v.z + v.w*v.w;
    }
    #pragma unroll
    for (int m = 1; m < 64; m <<= 1){ s += __shfl_xor(s, m); sq += __shfl_xor(sq, m); }
    __shared__ float2 acc[4];
    if ((threadIdx.x & 63) == 0) acc[threadIdx.x >> 6] = make_float2(s, sq);
    __syncthreads();
    if (threadIdx.x == 0){
      float S = 0.f, Q = 0.f;
      for (int i = 0; i < 4; ++i){ S += acc[i].x; Q += acc[i].y; }
      partial[b*64 + xb] = make_float2(S, Q);
    }
  } else {
    int id = (blk - 256) * 256 + threadIdx.x;
    if (id < 131072){
      Wqk[id] = f2bf(qkv_w[id]);
      if (id < 768) bias_qkv[id] = qkv_b[id];
    } else if (id < 196608){
      Wv[id - 131072] = f2bf(qkv_w[id]);
    } else {
      int j = id - 196608;
      Wp[j] = f2bf(proj_w[j]);
    }
  }
}

// ---------------- GroupNorm + transpose (final stat reduce done per-block, redundantly) ----------
__global__ __launch_bounds__(256) void norm_transpose_k(const float* __restrict__ x,
                                                        const float* __restrict__ gamma,
                                                        const float* __restrict__ beta,
                                                        const float2* __restrict__ partial,
                                                        unsigned short* __restrict__ xnt){
  __shared__ float tile[64][65];
  __shared__ float2 stt;
  const int b = blockIdx.z, n0 = blockIdx.x*64, c0 = blockIdx.y*64;
  const int t = threadIdx.x;
  if (t < 64){
    float2 p = partial[b*64 + t];
    float s = p.x, q = p.y;
    #pragma unroll
    for (int m = 1; m < 64; m <<= 1){ s += __shfl_xor(s, m); q += __shfl_xor(q, m); }
    if (t == 0){
      const float inv = 1.0f/1048576.0f;
      float mean = s*inv;
      float var  = q*inv - mean*mean;
      stt = make_float2(mean, rsqrtf(var + 1e-6f));
    }
  }
  __syncthreads();
  const float2 st = stt;
  const int col = t & 63, rb = t >> 6;
  #pragma unroll
  for (int i = 0; i < 16; ++i){
    int rr = i*4 + rb;
    float xv = x[((size_t)b*256 + c0 + rr)*4096 + n0 + col];
    tile[rr][col] = (xv - st.x) * st.y * gamma[c0+rr] + beta[c0+rr];
  }
  __syncthreads();
  #pragma unroll
  for (int i = 0; i < 16; ++i){
    int nr = i*4 + rb;
    xnt[((size_t)b*4096 + n0 + nr)*256 + c0 + col] = f2bf(tile[col][nr]);
  }
}

// ---------------- NT GEMM (R17 staging; used only for fused QKV) ----------------
// gn<512 -> fp8 qk8[b][gm][gn] (ldc=512); gn>=512 -> fp8 V A-frag tile
//   with c=gn-512, n=gm: vt8[b*1MB + ((n>>4)*8 + (c>>5))*512 + (((c&31)*16 + (n&15)) ^ ((c>>3&1)<<3))]
__global__ __launch_bounds__(256) void gemm_nt_k(const unsigned short* __restrict__ A,
                                                 const unsigned short* __restrict__ B,
                                                 int lda, int ldb, long sA, long sB,
                                                 const float* __restrict__ bias_n,
                                                 unsigned char* __restrict__ out8,
                                                 unsigned char* __restrict__ out8v,
                                                 int ldc, long sC){
  __shared__ unsigned short As[64][40];
  __shared__ unsigned short Bs[64][40];
  const int b  = blockIdx.z;
  const int m0 = blockIdx.x * 64, n0 = blockIdx.y * 64;
  const unsigned short* Ab = A + (size_t)b * sA;
  const unsigned short* Bb = B + (size_t)b * sB;
  const int t = threadIdx.x;
  const int lane = t & 63, w = t >> 6;
  const int g = lane >> 4, r = lane & 15;
  const int wm = (w >> 1) * 32, wn = (w & 1) * 32;
  const int lrow = t >> 2, lcol = (t & 3) * 8;
  f32x4 acc00 = {0,0,0,0}, acc01 = {0,0,0,0}, acc10 = {0,0,0,0}, acc11 = {0,0,0,0};
  for (int ks = 0; ks < 8; ++ks){
    short8 av = *(const short8*)(Ab + (size_t)(m0 + lrow) * lda + ks*32 + lcol);
    short8 bv = *(const short8*)(Bb + (size_t)(n0 + lrow) * ldb + ks*32 + lcol);
    __syncthreads();
    *(short8*)&As[lrow][lcol] = av;
    *(short8*)&Bs[lrow][lcol] = bv;
    __syncthreads();
    short8 af0 = *(const short8*)&As[wm + r][g*8];
    short8 af1 = *(const short8*)&As[wm + 16 + r][g*8];
    short8 bf0 = *(const short8*)&Bs[wn + r][g*8];
    short8 bf1 = *(const short8*)&Bs[wn + 16 + r][g*8];
    acc00 = __builtin_amdgcn_mfma_f32_16x16x32_bf16(af0, bf0, acc00, 0, 0, 0);
    acc01 = __builtin_amdgcn_mfma_f32_16x16x32_bf16(af0, bf1, acc01, 0, 0, 0);
    acc10 = __builtin_amdgcn_mfma_f32_16x16x32_bf16(af1, bf0, acc10, 0, 0, 0);
    acc11 = __builtin_amdgcn_mfma_f32_16x16x32_bf16(af1, bf1, acc11, 0, 0, 0);
  }
  f32x4 accs[2][2] = {{acc00, acc01},{acc10, acc11}};
  #pragma unroll
  for (int mi = 0; mi < 2; ++mi)
    #pragma unroll
    for (int ni = 0; ni < 2; ++ni)
      #pragma unroll
      for (int j = 0; j < 4; ++j){
        int gm = m0 + wm + mi*16 + g*4 + j;
        int gn = n0 + wn + ni*16 + r;
        float vv = accs[mi][ni][j] + bias_n[gn];
        unsigned char v8 = (unsigned char)(cvt2_fp8(vv, vv) & 0xff);
        if (gn >= 512){
          int c = gn - 512, n = gm;
          int inner = (((c & 31)*16 + (n & 15)) ^ (((c >> 3) & 1) << 3));
          out8v[(size_t)b*1048576 + (size_t)((n >> 4)*8 + (c >> 5))*512 + inner] = v8;
        } else {
          out8[(size_t)b*sC + (size_t)gm*ldc + gn] = v8;
        }
      }
}

// ---------------- flash attention: 4 waves x (32 q, full 32-k, 256 c); fp8 QK AND fp8 PV ----------
// po4 layout: combo*2MB + (cg*4096 + q)*8 bytes, cg = c/4, 4 bf16 per entry (c run of 4).
__global__ __launch_bounds__(256, 2) void attn_k(const unsigned char* __restrict__ qk8,
                                                 const unsigned char* __restrict__ vt8,
                                                 char* __restrict__ po4,
                                                 float* __restrict__ ml){
  __shared__ __align__(16) char smem[32768];   // dbuf 2 x (K 8KB | V 8KB)
  const int id = blockIdx.x;
  const int combo = id & 15, qb = id >> 4;     // combo&7 -> XCD (K/V L2-resident per combo)
  const int b = combo >> 2, ks = combo & 3;
  const int q0 = qb * 128;
  const int t = threadIdx.x, lane = t & 63, w = t >> 6;   // w = q-subblock 0..3
  const int hi = lane >> 5, l31 = lane & 31;
  const unsigned char* qkb = qk8 + (size_t)b * 4096 * 512;
  const unsigned char* vtb = vt8 + (size_t)b * 1048576;
  const float SQL2 = 0.0625f * 1.44269504088896340736f;

  // ---- Q fp8 fragments: wave owns q-rows q0 + w*32 + l31 (B-operand) ----
  unsigned long long qf[16];
  {
    const unsigned char* qrow = qkb + (size_t)(q0 + w*32 + l31) * 512;
    #pragma unroll
    for (int s = 0; s < 16; ++s) qf[s] = *(const unsigned long long*)(qrow + s*16 + hi*8);
  }

  // stage K tile (32 rows x 256B fp8): 2 loads/thread, XOR-swizzled source, linear dest
  auto stageK = [&](int kt, char* buf){
    const int kbase = ks*1024 + kt*32;
    #pragma unroll
    for (int i2 = 0; i2 < 2; ++i2){
      int ci = (w*2 + i2)*64 + lane;
      int r = ci >> 4;
      const unsigned char* src = qkb + (size_t)(kbase + r)*512 + 256
                               + (((ci & 15) ^ (r & 15)) * 16);
      gload16(src, buf + (w*2 + i2)*1024);
    }
  };
  // stage V (16 fp8 tiles of 512B): 2 loads/thread (each load covers 2 tiles)
  auto stageV = [&](int kt, char* buf){
    const int kbase = ks*1024 + kt*32;
    #pragma unroll
    for (int i = 0; i < 2; ++i){
      int tp = (w*2 + i)*2;              // first tile of this 1KB pair
      int tile = tp + (lane >> 5);       // kslice = tile>>3, c-block = tile&7
      const unsigned char* src = vtb + (size_t)((kbase >> 4) + (tile >> 3))*4096
                               + (tile & 7)*512 + (lane & 31)*16;
      gload16(src, buf + 8192 + tp*512);
    }
  };
  stageK(0, smem);
  stageV(0, smem);

  f32x16 O[8];     // full 256 c for this wave's 32 q
  #pragma unroll
  for (int cb = 0; cb < 8; ++cb)
    #pragma unroll
    for (int jj = 0; jj < 16; ++jj) O[cb][jj] = 0.f;
  float lrun = 0.f;
  const int ksw = (l31 & 15) << 4;
  const int vsw = ((l31 >> 3) & 1) << 3;
  const int vbase = l31*16 + hi*8;

  for (int kt = 0; kt < 32; ++kt){
    char* cur = smem + (kt & 1)*16384;
    char* nxt = smem + ((kt + 1) & 1)*16384;

    WAITV(0);     // tile-kt stages landed (issued a full iteration ago)
    BARRIER();    // all waves' tile kt visible; prev buffer fully consumed

    int ktn = (kt < 31) ? kt + 1 : 31;
    stageK(ktn, nxt);   // issue next tile now: covered by QK + SM + PV
    stageV(ktn, nxt);

    // ---- S^T = K . Q : 16 fp8 MFMA, 2 chains (full 32 k-rows) ----
    f32x16 Sa, Sb;
    #pragma unroll
    for (int jj = 0; jj < 16; ++jj){ Sa[jj] = 0.f; Sb[jj] = 0.f; }
    const char* kp = cur + l31*256;
    __builtin_amdgcn_s_setprio(1);
    #pragma unroll
    for (int s = 0; s < 8; ++s){
      unsigned long long k0 = *(const unsigned long long*)(kp + (((2*s  )*16 + hi*8) ^ ksw));
      unsigned long long k1 = *(const unsigned long long*)(kp + (((2*s+1)*16 + hi*8) ^ ksw));
      Sa = __builtin_amdgcn_mfma_f32_32x32x16_fp8_fp8((long long)k0, (long long)qf[2*s  ], Sa, 0, 0, 0);
      Sb = __builtin_amdgcn_mfma_f32_32x32x16_fp8_fp8((long long)k1, (long long)qf[2*s+1], Sb, 0, 0, 0);
    }
    __builtin_amdgcn_s_setprio(0);

    // ---- softmax (no max; constant cancels): p = exp2(S*scale), pack to fp8 ----
    float p[16];
    #pragma unroll
    for (int jj = 0; jj < 16; ++jj)
      p[jj] = __builtin_amdgcn_exp2f((Sa[jj] + Sb[jj]) * SQL2);
    lrun += ((p[0]+p[1]) + (p[2]+p[3])) + ((p[4]+p[5]) + (p[6]+p[7]))
          + ((p[8]+p[9]) + (p[10]+p[11])) + ((p[12]+p[13]) + (p[14]+p[15]));
    unsigned A0 = (unsigned)__builtin_amdgcn_cvt_pk_fp8_f32(p[0],  p[1],  0, false);
    A0 = (unsigned)__builtin_amdgcn_cvt_pk_fp8_f32(p[2],  p[3],  (int)A0, true);
    unsigned B0 = (unsigned)__builtin_amdgcn_cvt_pk_fp8_f32(p[4],  p[5],  0, false);
    B0 = (unsigned)__builtin_amdgcn_cvt_pk_fp8_f32(p[6],  p[7],  (int)B0, true);
    unsigned A1 = (unsigned)__builtin_amdgcn_cvt_pk_fp8_f32(p[8],  p[9],  0, false);
    A1 = (unsigned)__builtin_amdgcn_cvt_pk_fp8_f32(p[10], p[11], (int)A1, true);
    unsigned B1 = (unsigned)__builtin_amdgcn_cvt_pk_fp8_f32(p[12], p[13], 0, false);
    B1 = (unsigned)__builtin_amdgcn_cvt_pk_fp8_f32(p[14], p[15], (int)B1, true);
    asm("v_permlane32_swap_b32 %0, %1" : "+v"(A0), "+v"(B0));
    asm("v_permlane32_swap_b32 %0, %1" : "+v"(A1), "+v"(B1));
    long long pb0 = (long long)(((unsigned long long)B0 << 32) | A0);  // k 0..15
    long long pb1 = (long long)(((unsigned long long)B1 << 32) | A1);  // k 16..31

    // ---- O += V . P^T : 8 c-blocks x 2 k-slices, all fp8 ----
    const char* Vt = cur + 8192;
    __builtin_amdgcn_s_setprio(1);
    #pragma unroll
    for (int cb = 0; cb < 8; ++cb){
      unsigned long long v0 = *(const unsigned long long*)(Vt + (0*8 + cb)*512 + (vbase ^ vsw));
      O[cb] = __builtin_amdgcn_mfma_f32_32x32x16_fp8_fp8((long long)v0, pb0, O[cb], 0, 0, 0);
      unsigned long long v1 = *(const unsigned long long*)(Vt + (1*8 + cb)*512 + (vbase ^ vsw));
      O[cb] = __builtin_amdgcn_mfma_f32_32x32x16_fp8_fp8((long long)v1, pb1, O[cb], 0, 0, 0);
    }
    __builtin_amdgcn_s_setprio(0);
  }
  WAITV(0);   // drain tail stages before endpgm

  // ---- epilogue: run-packed po4 (8B per c-quad, coalesced) + l partials ----
  float lf = lrun + __shfl_xor(lrun, 32);
  const int qg = q0 + w*32 + l31;
  unsigned long long* pob = (unsigned long long*)(po4 + (size_t)combo * 2097152);
  #pragma unroll
  for (int cb = 0; cb < 8; ++cb)
    #pragma unroll
    for (int J = 0; J < 4; ++J){
      unsigned lo = cvtpk_bf16(O[cb][4*J+0], O[cb][4*J+1]);
      unsigned hi2 = cvtpk_bf16(O[cb][4*J+2], O[cb][4*J+3]);
      int cg = cb*8 + J*2 + hi;
      pob[(size_t)cg*4096 + qg] = ((unsigned long long)hi2 << 32) | lo;
    }
  if (lane < 32)
    ml[(size_t)combo*4096 + qg] = lf;
}

// ---------------- fused merge + proj: out[b][o][n] = Wp·(Σ po)·inv + b + x ----------------
// Block: 32 n x 256 o for one batch. A = Wp frags (LDS-staged), B = po4-derived frags (regs).
__global__ __launch_bounds__(256, 2) void projm_k(const char* __restrict__ po4,
                                                  const float* __restrict__ ml,
                                                  const unsigned short* __restrict__ Wp,
                                                  const float* __restrict__ proj_b,
                                                  const float* __restrict__ x,
                                                  float* __restrict__ out){
  __shared__ __align__(16) char wsm[32768];   // dbuf 2 x 16KB Wp fragment tiles
  const int b = blockIdx.y, n0 = blockIdx.x * 32;
  const int t = threadIdx.x, lane = t & 63, w = t >> 6;
  const int hi = lane >> 5, l31 = lane & 31;
  const int n = n0 + l31;

  float L = 0.f;
  #pragma unroll
  for (int ksv = 0; ksv < 4; ++ksv) L += ml[(size_t)(b*4 + ksv)*4096 + n];
  float inv = 1.0f / L;

  const char* pob[4];
  #pragma unroll
  for (int ksv = 0; ksv < 4; ++ksv) pob[ksv] = po4 + (size_t)(b*4 + ksv)*2097152;

  // stage Wp fragment tiles: tile = ot*2 + ks2 (ot = o/32, ks2 = k-slice), 1KB each
  auto stageW = [&](int kstep, char* buf){
    #pragma unroll
    for (int i = 0; i < 4; ++i){
      int tile = w*4 + i, ot = tile >> 1, ks2 = tile & 1;
      const unsigned short* src = Wp + (size_t)(ot*32 + l31)*256 + kstep*32 + ks2*16 + hi*8;
      gload16(src, buf + tile*1024);
    }
  };
  stageW(0, wsm);

  f32x16 acc0, acc1;
  #pragma unroll
  for (int jj = 0; jj < 16; ++jj){ acc0[jj] = 0.f; acc1[jj] = 0.f; }

  for (int kstep = 0; kstep < 8; ++kstep){
    char* cur = wsm + (kstep & 1)*16384;
    char* nxt = wsm + ((kstep + 1) & 1)*16384;
    WAITV(0);
    BARRIER();
    if (kstep < 7) stageW(kstep + 1, nxt);

    // build ho B-frags for the 2 k-slices: sum 4 combos of po4 runs
    short8 hf[2];
    #pragma unroll
    for (int ks2 = 0; ks2 < 2; ++ks2){
      int cg = kstep*8 + ks2*4 + hi*2;
      float s[8];
      #pragma unroll
      for (int j = 0; j < 8; ++j) s[j] = 0.f;
      #pragma unroll
      for (int ksv = 0; ksv < 4; ++ksv){
        unsigned long long a = *(const unsigned long long*)(pob[ksv] + ((size_t)cg*4096 + n)*8);
        unsigned long long c = *(const unsigned long long*)(pob[ksv] + ((size_t)(cg+1)*4096 + n)*8);
        s[0] += bf2f((unsigned short)a);        s[1] += bf2f((unsigned short)(a >> 16));
        s[2] += bf2f((unsigned short)(a >> 32));s[3] += bf2f((unsigned short)(a >> 48));
        s[4] += bf2f((unsigned short)c);        s[5] += bf2f((unsigned short)(c >> 16));
        s[6] += bf2f((unsigned short)(c >> 32));s[7] += bf2f((unsigned short)(c >> 48));
      }
      unsigned u0 = cvtpk_bf16(s[0], s[1]), u1 = cvtpk_bf16(s[2], s[3]);
      unsigned u2 = cvtpk_bf16(s[4], s[5]), u3 = cvtpk_bf16(s[6], s[7]);
      i32x4 uv = {(int)u0, (int)u1, (int)u2, (int)u3};
      hf[ks2] = __builtin_bit_cast(short8, uv);
    }

    // MFMA: 2 o-tiles x 2 k-slices
    #pragma unroll
    for (int ks2 = 0; ks2 < 2; ++ks2){
      short8 wf0 = *(const short8*)(cur + ((w*2 + 0)*2 + ks2)*1024 + lane*16);
      acc0 = __builtin_amdgcn_mfma_f32_32x32x16_bf16(wf0, hf[ks2], acc0, 0, 0, 0);
      short8 wf1 = *(const short8*)(cur + ((w*2 + 1)*2 + ks2)*1024 + lane*16);
      acc1 = __builtin_amdgcn_mfma_f32_32x32x16_bf16(wf1, hf[ks2], acc1, 0, 0, 0);
    }
  }

  // C-write: out[b][o][n] = acc*inv + proj_b[o] + x
  #pragma unroll
  for (int ot = 0; ot < 2; ++ot){
    const f32x16& A = ot ? acc1 : acc0;
    #pragma unroll
    for (int jj = 0; jj < 16; ++jj){
      int o = w*64 + ot*32 + (jj & 3) + 8*(jj >> 2) + 4*hi;
      size_t off = ((size_t)(b*256 + o))*4096 + n;
      out[off] = A[jj]*inv + proj_b[o] + x[off];
    }
  }
}

// ---------------- launch ----------------
extern "C" void kernel_launch(void* const* d_in, const int* in_sizes, int n_in,
                              void* d_out, int out_size, void* d_ws, size_t ws_size,
                              hipStream_t stream){
  const float* x      = (const float*)d_in[0];
  const float* gamma  = (const float*)d_in[1];
  const float* beta   = (const float*)d_in[2];
  const float* qkv_w  = (const float*)d_in[3];
  const float* qkv_b  = (const float*)d_in[4];
  const float* proj_w = (const float*)d_in[5];
  const float* proj_b = (const float*)d_in[6];
  float* out = (float*)d_out;
  char* ws = (char*)d_ws;

  float2* partial        = (float2*)(ws + 0);
  float*  bias_qkv       = (float*)(ws + 4096);               // 768 f32
  unsigned short* Wqk    = (unsigned short*)(ws + 8192);      // 512x256 bf16 (contiguous with Wv)
  unsigned short* Wv     = (unsigned short*)(ws + 270336);    // 256x256
  unsigned short* Wp     = (unsigned short*)(ws + 401408);    // 256x256
  unsigned short* xnt    = (unsigned short*)(ws + 532480);    // 4x4096x256 bf16 (8.4 MB)
  unsigned char*  qk8    = (unsigned char*)(ws + 8921088);    // 4x4096x512 fp8 (8.4 MB)
  unsigned char*  vt8    = (unsigned char*)(ws + 17309696);   // 4x1MB fp8 V tiles (4.2 MB)
  char*           po4    = (char*)(ws + 25698304);            // 16 combos x 2MB run-packed bf16
  float*          ml     = (float*)(ws + 59252736);           // 16x4096 f32 (256 KB)

  fused_pre_k<<<1280, 256, 0, stream>>>(x, partial, qkv_w, qkv_b, proj_w,
                                        Wqk, Wv, Wp, bias_qkv);
  norm_transpose_k<<<dim3(64,4,4), 256, 0, stream>>>(x, gamma, beta, partial, xnt);
  // fused q,k,v GEMM: N=768 (gn<512 -> qk8, gn>=512 -> vt8 tiles); single pass over xnt
  gemm_nt_k<<<dim3(64,12,4), 256, 0, stream>>>(xnt, Wqk, 256, 256, 4096L*256, 0,
      bias_qkv, qk8, vt8, 512, 4096L*512);
  attn_k<<<dim3(512), 256, 0, stream>>>(qk8, vt8, po4, ml);
  // fused merge + projection + residual
  projm_k<<<dim3(128, 4), 256, 0, stream>>>(po4, ml, Wp, proj_b, x, out);
}